// Round 13
// baseline (288.792 us; speedup 1.0000x reference)
//
#include <hip/hip_runtime.h>
#include <hip/hip_cooperative_groups.h>
#include <math.h>

namespace cg = cooperative_groups;

#define NROWS 8192
#define DDIM  128
#define K20   28.853900817779268f        // 20 * log2(e)
#define K2    (K20 * K20)                // 832.5476
#define DTHR  8.3255f                    // 0.01 * K2 : self-pair mask (real pairs >> this)

typedef _Float16 f16x8 __attribute__((ext_vector_type(8)));
typedef _Float16 f16x4 __attribute__((ext_vector_type(4)));
typedef _Float16 f16x2 __attribute__((ext_vector_type(2)));
typedef float    f32x4 __attribute__((ext_vector_type(4)));

typedef __attribute__((address_space(3))) uint32_t       lds_u32;
typedef const __attribute__((address_space(1))) uint32_t glb_u32;

#ifndef __has_builtin
#define __has_builtin(x) 0
#endif
#if __has_builtin(__builtin_amdgcn_fdot2)
#define HAVE_FDOT2 1
#else
#define HAVE_FDOT2 0
#endif

// Fragment-major layout for mfma_f32_16x16x32_f16 (16-row groups):
//   xf[g*2048 + kk*512 + l*8 + j] = x[i = g*16 + (l&15)][k = kk*32 + (l>>4)*8 + j]
// ws layout (floats after xf): sums[0..N) = nL (sum exp(-40d)), [N..2N) = nS (sum exp(-20d))

// ================= phase 1: fp32 -> f16 frag-major + zero sums/out =================
__device__ __forceinline__ void convert_phase(const float* __restrict__ x,
                                              _Float16* __restrict__ xf,
                                              float* __restrict__ sums,
                                              float* __restrict__ out,
                                              int bid, int tid) {
    int idx = (bid * 256 + tid) * 4;                   // flat (i,k) element index
    float4 v = *(const float4*)(x + idx);
    f16x4 h = { (_Float16)v.x, (_Float16)v.y, (_Float16)v.z, (_Float16)v.w };
    const int i = idx >> 7, k = idx & 127;             // k multiple of 4
    const int lane = (((k >> 3) & 3) << 4) | (i & 15);
    const int dst = (i >> 4) * 2048 + (k >> 5) * 512 + lane * 8 + (k & 7);
    *(f16x4*)(xf + dst) = h;
    if (tid < 16) sums[bid * 16 + tid] = 0.0f;         // 1024*16 = 2*NROWS
    if (bid == 0 && tid == 0) out[0] = 0.0f;
}

// ================= phase 2: LDS-staged pair core (verified R12) =================
__device__ __forceinline__ void pair_phase(const _Float16* __restrict__ xf,
                                           float* __restrict__ sums,
                                           int bid, int tid,
                                           _Float16 (*buf)[4096]) {
    const int bx = bid & 63;                      // row block (128 rows)
    const int by = bid >> 6;                      // col segment (512 cols)
    const int w = tid >> 6;
    const int lane = tid & 63;
    const int ig = bx * 4 + w;                    // 32-row strip, 0..255
    const int i0 = ig * 32;
    const int gc0 = by * 16;                      // first 32-col group of segment

    const _Float16* ab = xf + (size_t)(ig * 2) * 2048 + lane * 8;
    f16x8 a0[4], a1[4];
    #pragma unroll
    for (int kk = 0; kk < 4; ++kk) {
        a0[kk] = *(const f16x8*)(ab + kk * 512);
        a1[kk] = *(const f16x8*)(ab + 2048 + kk * 512);
    }

    float nL[8], nS[8];
    #pragma unroll
    for (int r = 0; r < 8; ++r) { nL[r] = 0.f; nS[r] = 0.f; }

    auto STAGE = [&](int bi, int gc) {
        const _Float16* s = xf + (size_t)gc * 4096 + tid * 8;
        __builtin_amdgcn_global_load_lds((glb_u32*)s,
                                         (lds_u32*)&buf[bi][tid * 8], 16, 0, 0);
        __builtin_amdgcn_global_load_lds((glb_u32*)(s + 2048),
                                         (lds_u32*)&buf[bi][2048 + tid * 8], 16, 0, 0);
    };
    auto EPI = [&](const f32x4 acc, int q0) {
        #pragma unroll
        for (int r = 0; r < 4; ++r) {
            float d2s = fmaf(-2.0f * K2, acc[r], 2.0f * K2);   // (20*log2e)^2 * d^2
            float ds  = __builtin_amdgcn_sqrtf(d2s);           // NaN on self, masked
            float tt  = __builtin_amdgcn_exp2f(-ds);           // exp(-20 d)
            tt = (d2s < DTHR) ? 0.0f : tt;                     // exact self exclusion
            nS[q0 + r] += tt;
            nL[q0 + r] = fmaf(tt, tt, nL[q0 + r]);             // exp(-40 d)
        }
    };
    auto COMPUTE = [&](int bi) {
        #pragma unroll
        for (int h = 0; h < 2; ++h) {
            f32x4 acc0 = {0.f,0.f,0.f,0.f}, acc1 = {0.f,0.f,0.f,0.f};
            #pragma unroll
            for (int kk = 0; kk < 4; ++kk) {
                f16x8 b = *(const f16x8*)&buf[bi][h * 2048 + kk * 512 + lane * 8];
                acc0 = __builtin_amdgcn_mfma_f32_16x16x32_f16(a0[kk], b, acc0, 0, 0, 0);
                acc1 = __builtin_amdgcn_mfma_f32_16x16x32_f16(a1[kk], b, acc1, 0, 0, 0);
            }
            EPI(acc0, 0);
            EPI(acc1, 4);
        }
    };

    STAGE(0, gc0);
    __syncthreads();
    for (int g = 0; g < 16; ++g) {
        if (g < 15) STAGE((g + 1) & 1, gc0 + g + 1);
        COMPUTE(g & 1);
        __syncthreads();   // (a) stage g+1 complete  (b) buf[g&1] free for reuse
    }

    // reduce across the 16 column-lanes; C/D map: col=lane&15,
    // row = i0 + s*16 + (lane>>4)*4 + r  (m89/m91)
    #pragma unroll
    for (int s = 0; s < 2; ++s) {
        #pragma unroll
        for (int r = 0; r < 4; ++r) {
            float aa = nL[s * 4 + r], ss = nS[s * 4 + r];
            #pragma unroll
            for (int m = 1; m < 16; m <<= 1) {
                aa += __shfl_xor(aa, m, 64);
                ss += __shfl_xor(ss, m, 64);
            }
            if ((lane & 15) == 0) {
                const int row = i0 + s * 16 + (lane >> 4) * 4 + r;
                atomicAdd(&sums[row], aa);
                atomicAdd(&sums[NROWS + row], ss);
            }
        }
    }
}

// ================= phase 3: finalize, 8 rows per block (tid < 64) =================
__device__ __forceinline__ void finalize_phase(const _Float16* __restrict__ xf,
                                               const float* __restrict__ sums,
                                               float* __restrict__ out,
                                               int bid, int tid) {
    if (tid >= 64) return;
    const int i = bid * 8 + (tid >> 3);           // row
    const int j = tid & 7;                        // partner slot
    const int g = i >> 4, ri = i & 15, ii = i & 7;
    const _Float16* base = xf + (size_t)g * 2048;

    float pL = 0.f, pS = 0.f, subL = 0.f, subS = 0.f;
    if (j != ii) {
        const int rj = ri - ii + j;               // same 16-row group (classes 8-aligned)
        float dot = 0.f;
        #pragma unroll
        for (int kk = 0; kk < 4; ++kk) {
            #pragma unroll
            for (int h = 0; h < 4; ++h) {
                f16x8 av = *(const f16x8*)(base + kk * 512 + ((h << 4) | ri) * 8);
                f16x8 bv = *(const f16x8*)(base + kk * 512 + ((h << 4) | rj) * 8);
#if HAVE_FDOT2
                #pragma unroll
                for (int u = 0; u < 4; ++u) {
                    f16x2 pa = { av[2 * u], av[2 * u + 1] };
                    f16x2 pb = { bv[2 * u], bv[2 * u + 1] };
                    dot = __builtin_amdgcn_fdot2(pa, pb, dot, false);
                }
#else
                #pragma unroll
                for (int u = 0; u < 8; ++u)
                    dot = fmaf((float)av[u], (float)bv[u], dot);
#endif
            }
        }
        float d2 = fmaf(-2.f, dot, 2.f);
        float d  = sqrtf(fmaxf(d2, 1e-12f));           // reference clamp
        float tt = __builtin_amdgcn_exp2f(-d * K20);   // exp(-20 d)
        pS = __builtin_amdgcn_exp2f(d * K20);          // exp(+20 d)
        pL = tt * tt;
        float tp = (d2 * K2 < DTHR) ? 0.f : tt;        // what pair_phase added
        subS = tp;
        subL = tp * tp;
    }

    #pragma unroll
    for (int m = 1; m < 8; m <<= 1) {
        pL   += __shfl_xor(pL, m, 64);
        pS   += __shfl_xor(pS, m, 64);
        subL += __shfl_xor(subL, m, 64);
        subS += __shfl_xor(subS, m, 64);
    }

    float v = 0.f;
    if (j == 0) {
        float nLv = sums[i] - subL;
        float nSv = sums[NROWS + i] - subS;
        float aLr  = 1.0f - pL / (pL + nLv);
        float posL = logf(pS) - 16.0f;    // log(sum exp(20(d-0.8)))
        float negL = logf(nSv) + 22.0f;   // log(sum exp(20(1.1-d)))
        v = aLr * (posL + negL);
    }
    #pragma unroll
    for (int m = 8; m < 64; m <<= 1) v += __shfl_xor(v, m, 64);
    if (tid == 0) atomicAdd(out, v * (1.0f / NROWS));
}

// ================= fused cooperative kernel =================
__global__ __launch_bounds__(256, 4) void fused_kernel(
        const float* __restrict__ x,
        _Float16* __restrict__ xf,
        float* __restrict__ sums,
        float* __restrict__ out) {
    __shared__ _Float16 buf[2][4096];
    cg::grid_group grid = cg::this_grid();
    const int bid = blockIdx.x, tid = threadIdx.x;

    convert_phase(x, xf, sums, out, bid, tid);
    grid.sync();
    pair_phase(xf, sums, bid, tid, buf);
    grid.sync();
    finalize_phase(xf, sums, out, bid, tid);
}

// ================= standalone fallback kernels (identical phases) =================
__global__ void convert_kernel(const float* __restrict__ x,
                               _Float16* __restrict__ xf,
                               float* __restrict__ sums,
                               float* __restrict__ out) {
    convert_phase(x, xf, sums, out, blockIdx.x, threadIdx.x);
}

__global__ __launch_bounds__(256, 4) void pair_kernel(
        const _Float16* __restrict__ xf,
        float* __restrict__ sums) {
    __shared__ _Float16 buf[2][4096];
    pair_phase(xf, sums, blockIdx.x, threadIdx.x, buf);
}

__global__ void finalize_kernel(const _Float16* __restrict__ xf,
                                const float* __restrict__ sums,
                                float* __restrict__ out) {
    finalize_phase(xf, sums, out, blockIdx.x, threadIdx.x);
}

extern "C" void kernel_launch(void* const* d_in, const int* in_sizes, int n_in,
                              void* d_out, int out_size, void* d_ws, size_t ws_size,
                              hipStream_t stream) {
    const float* x = (const float*)d_in[0];
    float* out = (float*)d_out;

    _Float16* xf = (_Float16*)d_ws;              // 2 MB, fragment-major
    float* sums  = (float*)(xf + NROWS * DDIM);  // 2*NROWS floats

    void* args[] = { (void*)&x, (void*)&xf, (void*)&sums, (void*)&out };
    hipError_t err = hipLaunchCooperativeKernel((const void*)fused_kernel,
                                                dim3(1024), dim3(256),
                                                args, 0, stream);
    if (err != hipSuccess) {
        // fallback: identical phases as 3 dispatches (== round-12 behavior)
        convert_kernel<<<1024, 256, 0, stream>>>(x, xf, sums, out);
        pair_kernel<<<1024, 256, 0, stream>>>(xf, sums);
        finalize_kernel<<<1024, 64, 0, stream>>>(xf, sums, out);
    }
}

// Round 14
// 90.157 us; speedup vs baseline: 3.2032x; 3.2032x over previous
//
#include <hip/hip_runtime.h>
#include <math.h>

#define NROWS 8192
#define DDIM  128
#define K20   28.853900817779268f        // 20 * log2(e)
#define K2    (K20 * K20)                // 832.5476
#define DTHR  8.3255f                    // 0.01 * K2 : self-pair mask (real pairs >> this)

typedef _Float16 f16x8 __attribute__((ext_vector_type(8)));
typedef _Float16 f16x4 __attribute__((ext_vector_type(4)));
typedef _Float16 f16x2 __attribute__((ext_vector_type(2)));
typedef float    f32x4 __attribute__((ext_vector_type(4)));

typedef __attribute__((address_space(3))) uint32_t       lds_u32;
typedef const __attribute__((address_space(1))) uint32_t glb_u32;

#ifndef __has_builtin
#define __has_builtin(x) 0
#endif
#if __has_builtin(__builtin_amdgcn_fdot2)
#define HAVE_FDOT2 1
#else
#define HAVE_FDOT2 0
#endif

// Fragment-major layout for mfma_f32_16x16x32_f16 (16-row groups):
//   xf[g*2048 + kk*512 + l*8 + j] = x[i = g*16 + (l&15)][k = kk*32 + (l>>4)*8 + j]
// ws layout (floats after xf): sums[0..N) = nL (sum exp(-40d)), [N..2N) = nS (sum exp(-20d))

// ---- fp32 -> f16 frag-major transform + zero sums/out (verified) ----
__global__ void convert_kernel(const float* __restrict__ x,
                               _Float16* __restrict__ xf,
                               float* __restrict__ sums,
                               float* __restrict__ out) {
    int idx = (blockIdx.x * 256 + threadIdx.x) * 4;    // flat (i,k) element index
    float4 v = *(const float4*)(x + idx);
    f16x4 h = { (_Float16)v.x, (_Float16)v.y, (_Float16)v.z, (_Float16)v.w };
    const int i = idx >> 7, k = idx & 127;             // k multiple of 4
    const int lane = (((k >> 3) & 3) << 4) | (i & 15);
    const int dst = (i >> 4) * 2048 + (k >> 5) * 512 + lane * 8 + (k & 7);
    *(f16x4*)(xf + dst) = h;
    if (threadIdx.x < 16) sums[blockIdx.x * 16 + threadIdx.x] = 0.0f;  // 1024*16 = 2*NROWS
    if (blockIdx.x == 0 && threadIdx.x == 0) out[0] = 0.0f;
}

// ---- LDS-staged pair kernel, software-pipelined one group deep.
//      R12 base (verified) with ONE change: iteration g issues STAGE(g+1),
//      then the MFMAs of group g, then the EPILOGUE of group g-1 -- so the
//      trans-pipe epilogue (independent register work) overlaps the MFMA
//      cluster instead of serializing after it. Two named accumulator sets
//      alternate (no runtime indexing -> no scratch). ----
__global__ __launch_bounds__(256, 4) void pair_kernel(
        const _Float16* __restrict__ xf,
        float* __restrict__ sums) {
    __shared__ _Float16 buf[2][4096];             // 2 x 8 KB B-group buffers

    const int tid = threadIdx.x;
    const int w = tid >> 6;
    const int lane = tid & 63;
    const int ig = blockIdx.x * 4 + w;            // 32-row strip, 0..255
    const int i0 = ig * 32;
    const int gc0 = blockIdx.y * 16;              // first 32-col group of segment

    // A fragments resident: 2 x 16-row frag sets x 4 k-chunks (1 KB loads)
    const _Float16* ab = xf + (size_t)(ig * 2) * 2048 + lane * 8;
    f16x8 a0[4], a1[4];
    #pragma unroll
    for (int kk = 0; kk < 4; ++kk) {
        a0[kk] = *(const f16x8*)(ab + kk * 512);
        a1[kk] = *(const f16x8*)(ab + 2048 + kk * 512);
    }

    float nL[8], nS[8];
    #pragma unroll
    for (int r = 0; r < 8; ++r) { nL[r] = 0.f; nS[r] = 0.f; }

    auto STAGE = [&](int bi, int gc) {
        const _Float16* s = xf + (size_t)gc * 4096 + tid * 8;
        __builtin_amdgcn_global_load_lds((glb_u32*)s,
                                         (lds_u32*)&buf[bi][tid * 8], 16, 0, 0);
        __builtin_amdgcn_global_load_lds((glb_u32*)(s + 2048),
                                         (lds_u32*)&buf[bi][2048 + tid * 8], 16, 0, 0);
    };
    auto EPI = [&](const f32x4 acc, int q0) {
        #pragma unroll
        for (int r = 0; r < 4; ++r) {
            float d2s = fmaf(-2.0f * K2, acc[r], 2.0f * K2);   // (20*log2e)^2 * d^2
            float ds  = __builtin_amdgcn_sqrtf(d2s);           // NaN on self, masked
            float tt  = __builtin_amdgcn_exp2f(-ds);           // exp(-20 d)
            tt = (d2s < DTHR) ? 0.0f : tt;                     // exact self exclusion
            nS[q0 + r] += tt;
            nL[q0 + r] = fmaf(tt, tt, nL[q0 + r]);             // exp(-40 d)
        }
    };
    // MFMAs of one 32-col group (both 16-col halves, both row strips)
    auto MFMAG = [&](int bi, f32x4& h0s0, f32x4& h0s1, f32x4& h1s0, f32x4& h1s1) {
        h0s0 = f32x4{0.f,0.f,0.f,0.f}; h0s1 = f32x4{0.f,0.f,0.f,0.f};
        h1s0 = f32x4{0.f,0.f,0.f,0.f}; h1s1 = f32x4{0.f,0.f,0.f,0.f};
        #pragma unroll
        for (int kk = 0; kk < 4; ++kk) {
            f16x8 b = *(const f16x8*)&buf[bi][kk * 512 + lane * 8];
            h0s0 = __builtin_amdgcn_mfma_f32_16x16x32_f16(a0[kk], b, h0s0, 0, 0, 0);
            h0s1 = __builtin_amdgcn_mfma_f32_16x16x32_f16(a1[kk], b, h0s1, 0, 0, 0);
        }
        #pragma unroll
        for (int kk = 0; kk < 4; ++kk) {
            f16x8 b = *(const f16x8*)&buf[bi][2048 + kk * 512 + lane * 8];
            h1s0 = __builtin_amdgcn_mfma_f32_16x16x32_f16(a0[kk], b, h1s0, 0, 0, 0);
            h1s1 = __builtin_amdgcn_mfma_f32_16x16x32_f16(a1[kk], b, h1s1, 0, 0, 0);
        }
    };

    f32x4 pA, pB, pC, pD;   // previous group's accumulators
    f32x4 cA, cB, cC, cD;   // current group's accumulators

    // prologue: stage group 0, then group 1; MFMA group 0 (no epilogue yet)
    STAGE(0, gc0);
    __syncthreads();
    STAGE(1, gc0 + 1);
    MFMAG(0, pA, pB, pC, pD);
    __syncthreads();                               // buf1 (group 1) staged

    // main loop: pairs (1,2),(3,4),...,(13,14); group 15 handled after
    for (int g = 1; g <= 13; g += 2) {
        STAGE(0, gc0 + g + 1);                     // stage group g+1 -> buf0
        MFMAG(1, cA, cB, cC, cD);                  // MFMA group g (buf1)
        EPI(pA, 0); EPI(pB, 4); EPI(pC, 0); EPI(pD, 4);   // epilogue group g-1
        __syncthreads();                           // buf0 (group g+1) staged

        STAGE(1, gc0 + g + 2);                     // stage group g+2 -> buf1
        MFMAG(0, pA, pB, pC, pD);                  // MFMA group g+1 (buf0)
        EPI(cA, 0); EPI(cB, 4); EPI(cC, 0); EPI(cD, 4);   // epilogue group g
        __syncthreads();                           // buf1 (group g+2) staged
    }
    // groups 14 (in p*) and 15 (in buf1)
    MFMAG(1, cA, cB, cC, cD);                      // MFMA group 15
    EPI(pA, 0); EPI(pB, 4); EPI(pC, 0); EPI(pD, 4);       // epilogue group 14
    EPI(cA, 0); EPI(cB, 4); EPI(cC, 0); EPI(cD, 4);       // epilogue group 15

    // reduce across the 16 column-lanes; C/D map: col=lane&15,
    // row = i0 + s*16 + (lane>>4)*4 + r  (m89/m91, verified)
    #pragma unroll
    for (int s = 0; s < 2; ++s) {
        #pragma unroll
        for (int r = 0; r < 4; ++r) {
            float aa = nL[s * 4 + r], ss = nS[s * 4 + r];
            #pragma unroll
            for (int m = 1; m < 16; m <<= 1) {
                aa += __shfl_xor(aa, m, 64);
                ss += __shfl_xor(ss, m, 64);
            }
            if ((lane & 15) == 0) {
                const int row = i0 + s * 16 + (lane >> 4) * 4 + r;
                atomicAdd(&sums[row], aa);
                atomicAdd(&sums[NROWS + row], ss);
            }
        }
    }
}

// ---- finalize + positive-pair correction, 8 threads per row (verified) ----
__global__ void finalize_kernel(const _Float16* __restrict__ xf,
                                const float* __restrict__ sums,
                                float* __restrict__ out) {
    const int tid = threadIdx.x;
    const int i = blockIdx.x * 32 + (tid >> 3);   // row
    const int j = tid & 7;                        // partner slot
    const int g = i >> 4, ri = i & 15, ii = i & 7;
    const _Float16* base = xf + (size_t)g * 2048;

    float pL = 0.f, pS = 0.f, subL = 0.f, subS = 0.f;
    if (j != ii) {
        const int rj = ri - ii + j;               // same 16-row group (classes 8-aligned)
        float dot = 0.f;
        #pragma unroll
        for (int kk = 0; kk < 4; ++kk) {
            #pragma unroll
            for (int h = 0; h < 4; ++h) {
                f16x8 av = *(const f16x8*)(base + kk * 512 + ((h << 4) | ri) * 8);
                f16x8 bv = *(const f16x8*)(base + kk * 512 + ((h << 4) | rj) * 8);
#if HAVE_FDOT2
                #pragma unroll
                for (int u = 0; u < 4; ++u) {
                    f16x2 pa = { av[2 * u], av[2 * u + 1] };
                    f16x2 pb = { bv[2 * u], bv[2 * u + 1] };
                    dot = __builtin_amdgcn_fdot2(pa, pb, dot, false);
                }
#else
                #pragma unroll
                for (int u = 0; u < 8; ++u)
                    dot = fmaf((float)av[u], (float)bv[u], dot);
#endif
            }
        }
        float d2 = fmaf(-2.f, dot, 2.f);
        float d  = sqrtf(fmaxf(d2, 1e-12f));           // reference clamp
        float tt = __builtin_amdgcn_exp2f(-d * K20);   // exp(-20 d)
        pS = __builtin_amdgcn_exp2f(d * K20);          // exp(+20 d)
        pL = tt * tt;
        float tp = (d2 * K2 < DTHR) ? 0.f : tt;        // what pair_kernel added
        subS = tp;
        subL = tp * tp;
    }

    #pragma unroll
    for (int m = 1; m < 8; m <<= 1) {
        pL   += __shfl_xor(pL, m, 64);
        pS   += __shfl_xor(pS, m, 64);
        subL += __shfl_xor(subL, m, 64);
        subS += __shfl_xor(subS, m, 64);
    }

    float v = 0.f;
    if (j == 0) {
        float nLv = sums[i] - subL;
        float nSv = sums[NROWS + i] - subS;
        float aLr  = 1.0f - pL / (pL + nLv);
        float posL = logf(pS) - 16.0f;    // log(sum exp(20(d-0.8)))
        float negL = logf(nSv) + 22.0f;   // log(sum exp(20(1.1-d)))
        v = aLr * (posL + negL);
    }
    #pragma unroll
    for (int m = 8; m < 64; m <<= 1) v += __shfl_xor(v, m, 64);

    __shared__ float partial[4];
    int wv = tid >> 6, lane = tid & 63;
    if (lane == 0) partial[wv] = v;
    __syncthreads();
    if (tid == 0) {
        float s = partial[0] + partial[1] + partial[2] + partial[3];
        atomicAdd(out, s * (1.0f / NROWS));
    }
}

extern "C" void kernel_launch(void* const* d_in, const int* in_sizes, int n_in,
                              void* d_out, int out_size, void* d_ws, size_t ws_size,
                              hipStream_t stream) {
    const float* x = (const float*)d_in[0];
    float* out = (float*)d_out;

    _Float16* xf = (_Float16*)d_ws;              // 2 MB, fragment-major
    float* sums  = (float*)(xf + NROWS * DDIM);  // 2*NROWS floats

    convert_kernel<<<NROWS * DDIM / (256 * 4), 256, 0, stream>>>(x, xf, sums, out);
    dim3 grid(NROWS / 128, NROWS / 512);         // 64 x 16 = 1024 blocks, 1 generation
    pair_kernel<<<grid, 256, 0, stream>>>(xf, sums);
    finalize_kernel<<<NROWS / 32, 256, 0, stream>>>(xf, sums, out);
}

// Round 17
// 88.740 us; speedup vs baseline: 3.2543x; 1.0160x over previous
//
#include <hip/hip_runtime.h>
#include <math.h>

#define NROWS 8192
#define DDIM  128
#define K20   28.853900817779268f        // 20 * log2(e)
#define K2    (K20 * K20)                // 832.5476
#define DTHR  8.3255f                    // 0.01 * K2 (finalize subtraction mimic only)

typedef _Float16 f16x8 __attribute__((ext_vector_type(8)));
typedef _Float16 f16x4 __attribute__((ext_vector_type(4)));
typedef _Float16 f16x2 __attribute__((ext_vector_type(2)));
typedef float    f32x4 __attribute__((ext_vector_type(4)));

#ifndef __has_builtin
#define __has_builtin(x) 0
#endif
#if __has_builtin(__builtin_amdgcn_fdot2)
#define HAVE_FDOT2 1
#else
#define HAVE_FDOT2 0
#endif

// Fragment-major layout for mfma_f32_16x16x32_f16 (16-row groups):
//   xf[g*2048 + kk*512 + l*8 + j] = x[i = g*16 + (l&15)][k = kk*32 + (l>>4)*8 + j]
// -> a wave's A/B fragment load for one k-chunk is one contiguous 1 KB dwordx4.
// ws layout (floats after xf): sums[0..N) = nL (sum exp(-40d)), [N..2N) = nS (sum exp(-20d))

// ---- fp32 -> f16 frag-major transform + zero sums/out ----
__global__ void convert_kernel(const float* __restrict__ x,
                               _Float16* __restrict__ xf,
                               float* __restrict__ sums,
                               float* __restrict__ out) {
    int idx = (blockIdx.x * 256 + threadIdx.x) * 4;    // flat (i,k) element index
    float4 v = *(const float4*)(x + idx);
    f16x4 h = { (_Float16)v.x, (_Float16)v.y, (_Float16)v.z, (_Float16)v.w };
    const int i = idx >> 7, k = idx & 127;             // k multiple of 4
    const int lane = (((k >> 3) & 3) << 4) | (i & 15);
    const int dst = (i >> 4) * 2048 + (k >> 5) * 512 + lane * 8 + (k & 7);
    *(f16x4*)(xf + dst) = h;
    if (threadIdx.x < 16) sums[blockIdx.x * 16 + threadIdx.x] = 0.0f;  // 1024*16 = 2*NROWS
    if (blockIdx.x == 0 && threadIdx.x == 0) out[0] = 0.0f;
}

// ---- main pair kernel, symmetric: only strictly-upper elements (j > i) are
//      accumulated, each contributing to row i (direct, row-sum reduce +
//      atomic) AND row j (mirror, col-sum reduce via LDS + atomic). Blocks
//      entirely below the diagonal exit immediately (1056 of 2048 survive).
//      Wave = 32-row strip x 256-col segment (16 tiles of 16 cols), B tiles
//      register-double-buffered. (Session-best configuration, R7.) ----
__global__ __launch_bounds__(256, 4) void pair_kernel(
        const _Float16* __restrict__ xf,
        float* __restrict__ sums) {
    // keep block iff its 256-col segment reaches above the diagonal:
    // max col (256*by+255) >= min row (128*bx)  <=>  2*by+2 > bx
    if (2 * blockIdx.y + 2 <= blockIdx.x) return;

    __shared__ float shcL[4][256], shcS[4][256];

    const int w = threadIdx.x >> 6;
    const int lane = threadIdx.x & 63;
    const int ig = blockIdx.x * 4 + w;            // 32-row strip, 0..255
    const int i0 = ig * 32;
    const int ct0 = blockIdx.y * 16;              // first 16-col tile of segment

    // A fragments resident: 2 strips x 4 k-chunks, one 1 KB coalesced load each
    const _Float16* ab = xf + (size_t)(ig * 2) * 2048 + lane * 8;
    f16x8 a0[4], a1[4];
    #pragma unroll
    for (int kk = 0; kk < 4; ++kk) {
        a0[kk] = *(const f16x8*)(ab + kk * 512);
        a1[kk] = *(const f16x8*)(ab + 2048 + kk * 512);
    }

    float nL[8], nS[8];
    #pragma unroll
    for (int r = 0; r < 8; ++r) { nL[r] = 0.f; nS[r] = 0.f; }

    const _Float16* bb = xf + (size_t)ct0 * 2048 + lane * 8;

    f16x8 b0[4], b1[4];
    #pragma unroll
    for (int kk = 0; kk < 4; ++kk) b0[kk] = *(const f16x8*)(bb + kk * 512);

    auto compute = [&](f16x8 (&b)[4], int g) {
        f32x4 acc0 = {0.f,0.f,0.f,0.f}, acc1 = {0.f,0.f,0.f,0.f};
        #pragma unroll
        for (int kk = 0; kk < 4; ++kk) {
            acc0 = __builtin_amdgcn_mfma_f32_16x16x32_f16(a0[kk], b[kk], acc0, 0, 0, 0);
            acc1 = __builtin_amdgcn_mfma_f32_16x16x32_f16(a1[kk], b[kk], acc1, 0, 0, 0);
        }
        const int jcol = (ct0 + g) * 16 + (lane & 15);   // this lane's column
        float cs = 0.f, cl = 0.f;
        #pragma unroll
        for (int s = 0; s < 2; ++s) {
            const int ib = i0 + s * 16 + ((lane >> 4) << 2);  // C/D row base (m89/m91)
            #pragma unroll
            for (int r = 0; r < 4; ++r) {
                float acc = s ? acc1[r] : acc0[r];            // static indices
                float d2s = fmaf(-2.0f * K2, acc, 2.0f * K2); // (20*log2e)^2 * d^2
                float ds  = __builtin_amdgcn_sqrtf(d2s);      // NaN on self, masked below
                float tt  = __builtin_amdgcn_exp2f(-ds);      // exp(-20 d)
                tt = (jcol > ib + r) ? tt : 0.0f;             // strictly-upper only
                nS[s * 4 + r] += tt;
                nL[s * 4 + r] = fmaf(tt, tt, nL[s * 4 + r]);  // exp(-40 d)
                cs += tt;
                cl = fmaf(tt, tt, cl);
            }
        }
        // mirror: reduce over the wave's 32 rows (row groups at lane bits 4,5)
        cs += __shfl_xor(cs, 16, 64);  cl += __shfl_xor(cl, 16, 64);
        cs += __shfl_xor(cs, 32, 64);  cl += __shfl_xor(cl, 32, 64);
        if (lane < 16) { shcS[w][g * 16 + lane] = cs; shcL[w][g * 16 + lane] = cl; }
    };

    // 16 col-tiles, 1-ahead register double buffer (wrap reload on last: harmless)
    for (int g = 0; g < 16; g += 2) {
        const _Float16* p1 = bb + (size_t)(g + 1) * 2048;
        #pragma unroll
        for (int kk = 0; kk < 4; ++kk) b1[kk] = *(const f16x8*)(p1 + kk * 512);
        compute(b0, g);
        const _Float16* p2 = bb + (size_t)((g + 2) & 15) * 2048;
        #pragma unroll
        for (int kk = 0; kk < 4; ++kk) b0[kk] = *(const f16x8*)(p2 + kk * 512);
        compute(b1, g + 1);
    }

    // direct row sums: reduce across the 16 column-lanes, atomic into sums[row]
    #pragma unroll
    for (int s = 0; s < 2; ++s) {
        #pragma unroll
        for (int r = 0; r < 4; ++r) {
            float aa = nL[s * 4 + r], ss = nS[s * 4 + r];
            #pragma unroll
            for (int m = 1; m < 16; m <<= 1) {
                aa += __shfl_xor(aa, m, 64);
                ss += __shfl_xor(ss, m, 64);
            }
            if ((lane & 15) == 0) {
                const int row = i0 + s * 16 + (lane >> 4) * 4 + r;
                atomicAdd(&sums[row], aa);
                atomicAdd(&sums[NROWS + row], ss);
            }
        }
    }

    // mirrored col sums: combine the 4 waves, one atomic per column
    __syncthreads();
    {
        const int c = threadIdx.x;                 // 256 threads = 256 segment cols
        const int col = ct0 * 16 + c;
        float mL = shcL[0][c] + shcL[1][c] + shcL[2][c] + shcL[3][c];
        float mS = shcS[0][c] + shcS[1][c] + shcS[2][c] + shcS[3][c];
        atomicAdd(&sums[col], mL);
        atomicAdd(&sums[NROWS + col], mS);
    }
}

// ---- finalize + positive-pair correction, 8 threads per row (1024 waves).
//      Thread j of row i computes the single partner jj=j (skipped when j==ii),
//      then a 3-step shuffle combine; lane j==0 finishes the per-row loss. ----
__global__ void finalize_kernel(const _Float16* __restrict__ xf,
                                const float* __restrict__ sums,
                                float* __restrict__ out) {
    const int tid = threadIdx.x;
    const int i = blockIdx.x * 32 + (tid >> 3);   // row
    const int j = tid & 7;                        // partner slot
    const int g = i >> 4, ri = i & 15, ii = i & 7;
    const _Float16* base = xf + (size_t)g * 2048;

    float pL = 0.f, pS = 0.f, subL = 0.f, subS = 0.f;
    if (j != ii) {
        const int rj = ri - ii + j;               // same 16-row group (classes 8-aligned)
        float dot = 0.f;
        #pragma unroll
        for (int kk = 0; kk < 4; ++kk) {
            #pragma unroll
            for (int h = 0; h < 4; ++h) {
                f16x8 av = *(const f16x8*)(base + kk * 512 + ((h << 4) | ri) * 8);
                f16x8 bv = *(const f16x8*)(base + kk * 512 + ((h << 4) | rj) * 8);
#if HAVE_FDOT2
                #pragma unroll
                for (int u = 0; u < 4; ++u) {
                    f16x2 pa = { av[2 * u], av[2 * u + 1] };
                    f16x2 pb = { bv[2 * u], bv[2 * u + 1] };
                    dot = __builtin_amdgcn_fdot2(pa, pb, dot, false);
                }
#else
                #pragma unroll
                for (int u = 0; u < 8; ++u)
                    dot = fmaf((float)av[u], (float)bv[u], dot);
#endif
            }
        }
        float d2 = fmaf(-2.f, dot, 2.f);
        float d  = sqrtf(fmaxf(d2, 1e-12f));           // reference clamp
        float tt = __builtin_amdgcn_exp2f(-d * K20);   // exp(-20 d)
        pS = __builtin_amdgcn_exp2f(d * K20);          // exp(+20 d)
        pL = tt * tt;
        float tp = (d2 * K2 < DTHR) ? 0.f : tt;        // what pair_kernel added
        subS = tp;
        subL = tp * tp;
    }

    // combine the 8 partner slots of this row
    #pragma unroll
    for (int m = 1; m < 8; m <<= 1) {
        pL   += __shfl_xor(pL, m, 64);
        pS   += __shfl_xor(pS, m, 64);
        subL += __shfl_xor(subL, m, 64);
        subS += __shfl_xor(subS, m, 64);
    }

    float v = 0.f;
    if (j == 0) {
        float nLv = sums[i] - subL;
        float nSv = sums[NROWS + i] - subS;
        float aLr  = 1.0f - pL / (pL + nLv);
        float posL = logf(pS) - 16.0f;    // log(sum exp(20(d-0.8)))
        float negL = logf(nSv) + 22.0f;   // log(sum exp(20(1.1-d)))
        v = aLr * (posL + negL);
    }
    #pragma unroll
    for (int m = 8; m < 64; m <<= 1) v += __shfl_xor(v, m, 64);

    __shared__ float partial[4];
    int wv = tid >> 6, lane = tid & 63;
    if (lane == 0) partial[wv] = v;
    __syncthreads();
    if (tid == 0) {
        float s = partial[0] + partial[1] + partial[2] + partial[3];
        atomicAdd(out, s * (1.0f / NROWS));
    }
}

extern "C" void kernel_launch(void* const* d_in, const int* in_sizes, int n_in,
                              void* d_out, int out_size, void* d_ws, size_t ws_size,
                              hipStream_t stream) {
    const float* x = (const float*)d_in[0];
    float* out = (float*)d_out;

    _Float16* xf = (_Float16*)d_ws;              // 2 MB, fragment-major
    float* sums  = (float*)(xf + NROWS * DDIM);  // 2*NROWS floats

    convert_kernel<<<NROWS * DDIM / (256 * 4), 256, 0, stream>>>(x, xf, sums, out);
    dim3 grid(NROWS / 128, NROWS / 256);         // 64 x 32; lower-triangle blocks exit
    pair_kernel<<<grid, 256, 0, stream>>>(xf, sums);
    finalize_kernel<<<NROWS / 32, 256, 0, stream>>>(xf, sums, out);
}